// Round 2
// baseline (271.009 us; speedup 1.0000x reference)
//
#include <hip/hip_runtime.h>
#include <hip/hip_bf16.h>

#define NPT 4  // nodes per thread in phase 1
#define EPT 2  // edges per thread in phase 2

__device__ __forceinline__ float fast_tanh(float x) {
    float ax = fabsf(x);
    float t = __expf(-2.f * ax);                       // in (0,1], no overflow
    float r = (1.f - t) * __builtin_amdgcn_rcpf(1.f + t);
    return copysignf(r, x);
}

__device__ __forceinline__ float fast_sigmoid(float s) {
    return __builtin_amdgcn_rcpf(1.f + __expf(-s));
}

// Phase 1: P[n][0:8] = X[n]·W1[0:64,:] + b1 ; P[n][8:16] = X[n]·W1[64:128,:]
__global__ __launch_bounds__(256) void phase1_kernel(
    const float* __restrict__ X, const float* __restrict__ W1,
    const float* __restrict__ b1, float* __restrict__ P, int BN) {
    __shared__ float w[64][16];   // row d: W1[d][0:8] ++ W1[64+d][0:8]
    __shared__ float bias[8];
    int t = threadIdx.x;
    for (int i = t; i < 1024; i += 256) {
        int d = i >> 3, j = i & 7;
        w[d & 63][((d >> 6) << 3) | j] = W1[i];
    }
    if (t < 8) bias[t] = b1[t];
    __syncthreads();

    int base = (blockIdx.x * 256 + t) * NPT;
    float acc[NPT][16];
#pragma unroll
    for (int p = 0; p < NPT; ++p) {
#pragma unroll
        for (int j = 0; j < 8; ++j) acc[p][j] = bias[j];
#pragma unroll
        for (int j = 8; j < 16; ++j) acc[p][j] = 0.f;
    }
    int nidx[NPT];
#pragma unroll
    for (int p = 0; p < NPT; ++p) {
        int n = base + p;
        nidx[p] = (n < BN) ? n : (BN - 1);   // clamp so loads stay in-bounds
    }

    for (int dc = 0; dc < 64; dc += 4) {
        float4 xv[NPT];
#pragma unroll
        for (int p = 0; p < NPT; ++p)
            xv[p] = *(const float4*)(X + (size_t)nidx[p] * 64 + dc);
#pragma unroll
        for (int dd = 0; dd < 4; ++dd) {
            const float* wr = &w[dc + dd][0];
            float4 wv0 = *(const float4*)(wr);
            float4 wv1 = *(const float4*)(wr + 4);
            float4 wv2 = *(const float4*)(wr + 8);
            float4 wv3 = *(const float4*)(wr + 12);
#pragma unroll
            for (int p = 0; p < NPT; ++p) {
                float xs = (dd == 0) ? xv[p].x : (dd == 1) ? xv[p].y
                         : (dd == 2) ? xv[p].z : xv[p].w;
                acc[p][0]  += xs * wv0.x;  acc[p][1]  += xs * wv0.y;
                acc[p][2]  += xs * wv0.z;  acc[p][3]  += xs * wv0.w;
                acc[p][4]  += xs * wv1.x;  acc[p][5]  += xs * wv1.y;
                acc[p][6]  += xs * wv1.z;  acc[p][7]  += xs * wv1.w;
                acc[p][8]  += xs * wv2.x;  acc[p][9]  += xs * wv2.y;
                acc[p][10] += xs * wv2.z;  acc[p][11] += xs * wv2.w;
                acc[p][12] += xs * wv3.x;  acc[p][13] += xs * wv3.y;
                acc[p][14] += xs * wv3.z;  acc[p][15] += xs * wv3.w;
            }
        }
    }
#pragma unroll
    for (int p = 0; p < NPT; ++p) {
        int n = base + p;
        if (n < BN) {
            float4* dst = (float4*)(P + (size_t)n * 16);
            dst[0] = make_float4(acc[p][0],  acc[p][1],  acc[p][2],  acc[p][3]);
            dst[1] = make_float4(acc[p][4],  acc[p][5],  acc[p][6],  acc[p][7]);
            dst[2] = make_float4(acc[p][8],  acc[p][9],  acc[p][10], acc[p][11]);
            dst[3] = make_float4(acc[p][12], acc[p][13], acc[p][14], acc[p][15]);
        }
    }
}

// Phase 2: per edge: h = tanh(P_o[ro] + P_i[ri]); out = sigmoid(h·W2 + b2)
// blockIdx.x & 7 == batch -> pins each batch's 3.2MB P-slice to one XCD's L2.
__global__ __launch_bounds__(256) void phase2_kernel(
    const int* __restrict__ Ri, const int* __restrict__ Ro,
    const float* __restrict__ P, const float* __restrict__ W2,
    const float* __restrict__ b2, float* __restrict__ out,
    int E, int N) {
    int b = blockIdx.x & 7;
    int e0 = ((blockIdx.x >> 3) * 256 + threadIdx.x) * EPT;
    float4 w2a = *(const float4*)W2;
    float4 w2b = *(const float4*)(W2 + 4);
    float bias2 = b2[0];
    const float4* Pv = (const float4*)P;
#pragma unroll
    for (int k = 0; k < EPT; ++k) {
        int e = e0 + k;
        if (e >= E) break;
        int idx = b * E + e;
        int ro = Ro[idx], ri = Ri[idx];
        int robase = (b * N + ro) << 2;   // float4 units; P row = 4 float4
        int ribase = (b * N + ri) << 2;
        float4 a0 = Pv[robase],     a1 = Pv[robase + 1];  // P_o(ro) (b1 folded)
        float4 c0 = Pv[ribase + 2], c1 = Pv[ribase + 3];  // P_i(ri)
        float s = bias2;
        s += fast_tanh(a0.x + c0.x) * w2a.x;
        s += fast_tanh(a0.y + c0.y) * w2a.y;
        s += fast_tanh(a0.z + c0.z) * w2a.z;
        s += fast_tanh(a0.w + c0.w) * w2a.w;
        s += fast_tanh(a1.x + c1.x) * w2b.x;
        s += fast_tanh(a1.y + c1.y) * w2b.y;
        s += fast_tanh(a1.z + c1.z) * w2b.z;
        s += fast_tanh(a1.w + c1.w) * w2b.w;
        out[idx] = fast_sigmoid(s);
    }
}

// Fallback if workspace is too small: one-pass per-edge evaluation.
__global__ __launch_bounds__(256) void direct_kernel(
    const float* __restrict__ X, const int* __restrict__ Ri, const int* __restrict__ Ro,
    const float* __restrict__ W1, const float* __restrict__ b1,
    const float* __restrict__ W2, const float* __restrict__ b2,
    float* __restrict__ out, int E, int N) {
    __shared__ float w[64][16];
    __shared__ float bias[8];
    int t = threadIdx.x;
    for (int i = t; i < 1024; i += 256) {
        int d = i >> 3, j = i & 7;
        w[d & 63][((d >> 6) << 3) | j] = W1[i];
    }
    if (t < 8) bias[t] = b1[t];
    __syncthreads();
    int b = blockIdx.x & 7;
    int e = (blockIdx.x >> 3) * 256 + t;
    if (e >= E) return;
    int idx = b * E + e;
    int ro = Ro[idx], ri = Ri[idx];
    const float* xo = X + (size_t)(b * N + ro) * 64;
    const float* xi = X + (size_t)(b * N + ri) * 64;
    float acc[8];
#pragma unroll
    for (int j = 0; j < 8; ++j) acc[j] = bias[j];
    for (int dc = 0; dc < 64; dc += 4) {
        float4 ov = *(const float4*)(xo + dc);
        float4 iv = *(const float4*)(xi + dc);
#pragma unroll
        for (int dd = 0; dd < 4; ++dd) {
            const float* wr = &w[dc + dd][0];
            float os = (dd == 0) ? ov.x : (dd == 1) ? ov.y : (dd == 2) ? ov.z : ov.w;
            float is = (dd == 0) ? iv.x : (dd == 1) ? iv.y : (dd == 2) ? iv.z : iv.w;
#pragma unroll
            for (int j = 0; j < 8; ++j)
                acc[j] += os * wr[j] + is * wr[8 + j];
        }
    }
    float4 w2a = *(const float4*)W2;
    float4 w2b = *(const float4*)(W2 + 4);
    float w2v[8] = {w2a.x, w2a.y, w2a.z, w2a.w, w2b.x, w2b.y, w2b.z, w2b.w};
    float s = b2[0];
#pragma unroll
    for (int j = 0; j < 8; ++j) s += fast_tanh(acc[j]) * w2v[j];
    out[idx] = fast_sigmoid(s);
}

extern "C" void kernel_launch(void* const* d_in, const int* in_sizes, int n_in,
                              void* d_out, int out_size, void* d_ws, size_t ws_size,
                              hipStream_t stream) {
    const float* X  = (const float*)d_in[0];
    const int*   Ri = (const int*)d_in[1];
    const int*   Ro = (const int*)d_in[2];
    const float* W1 = (const float*)d_in[3];
    const float* b1 = (const float*)d_in[4];
    const float* W2 = (const float*)d_in[5];
    const float* b2 = (const float*)d_in[6];
    float* out = (float*)d_out;

    const int B = 8;
    const int N = in_sizes[0] / (B * 64);   // 50000
    const int E = in_sizes[1] / B;          // 200000
    const int BN = B * N;

    size_t needP = (size_t)BN * 16 * sizeof(float);

    if (ws_size >= needP) {
        float* P = (float*)d_ws;
        int g1 = (BN + 256 * NPT - 1) / (256 * NPT);
        phase1_kernel<<<g1, 256, 0, stream>>>(X, W1, b1, P, BN);
        int bpb2 = (E + 256 * EPT - 1) / (256 * EPT);
        phase2_kernel<<<8 * bpb2, 256, 0, stream>>>(Ri, Ro, P, W2, b2, out, E, N);
    } else {
        int bpb = (E + 255) / 256;
        direct_kernel<<<8 * bpb, 256, 0, stream>>>(X, Ri, Ro, W1, b1, W2, b2, out, E, N);
    }
}

// Round 4
// 201.692 us; speedup vs baseline: 1.3437x; 1.3437x over previous
//
#include <hip/hip_runtime.h>
#include <hip/hip_bf16.h>

#define TILE 256   // nodes per block in phase 1 (NPT = 1)

__device__ __forceinline__ float fast_tanh(float x) {
    float ax = fabsf(x);
    float t = __expf(-2.f * ax);                       // in (0,1], no overflow
    float r = (1.f - t) * __builtin_amdgcn_rcpf(1.f + t);
    return copysignf(r, x);
}

__device__ __forceinline__ float fast_sigmoid(float s) {
    return __builtin_amdgcn_rcpf(1.f + __expf(-s));
}

// Phase 1: P[n][0:8] = X[n]·W1[0:64,:] + b1 ; P[n][8:16] = X[n]·W1[64:128,:]
// Coalesced global->LDS staging (XOR-swizzled float4 slots), one node/thread,
// W1/b1 read via uniform (scalar) loads so the LDS pipe only carries X.
__global__ __launch_bounds__(256, 2) void phase1_kernel(
    const float* __restrict__ X, const float* __restrict__ W1,
    const float* __restrict__ b1, float* __restrict__ P, int BN) {
    __shared__ float4 tile[TILE * 16];   // 64 KB; slot = node*16 + (f4 ^ (node&15))
    int t = threadIdx.x;
    int base = blockIdx.x * TILE;

    // Stage: 4096 float4 slots, 16 per thread, globally coalesced (1KB/wave/instr).
#pragma unroll
    for (int k = 0; k < 16; ++k) {
        int s = t + (k << 8);            // linear float4 index in tile
        int node = s >> 4;
        int f4 = s & 15;
        int gnode = base + node;
        gnode = (gnode < BN) ? gnode : (BN - 1);   // clamp: loads stay in-bounds
        float4 v = *(const float4*)(X + ((size_t)gnode << 6) + (f4 << 2));
        tile[(node << 4) | (f4 ^ (node & 15))] = v;
    }
    __syncthreads();

    // Compute: thread t owns node (base + t).
    float acc[16];
#pragma unroll
    for (int j = 0; j < 8; ++j) acc[j] = b1[j];      // uniform -> s_load
#pragma unroll
    for (int j = 8; j < 16; ++j) acc[j] = 0.f;

    const float4* row = tile + (t << 4);
    int sw = t & 15;
#pragma unroll
    for (int dc4 = 0; dc4 < 16; ++dc4) {
        float4 xv = row[dc4 ^ sw];                   // swizzled read, uniform banks
#pragma unroll
        for (int dd = 0; dd < 4; ++dd) {
            int d = (dc4 << 2) + dd;
            float xs = (dd == 0) ? xv.x : (dd == 1) ? xv.y : (dd == 2) ? xv.z : xv.w;
            const float* wo = W1 + d * 8;            // uniform addrs -> s_load
            const float* wi = W1 + (64 + d) * 8;
#pragma unroll
            for (int j = 0; j < 8; ++j) {
                acc[j]     += xs * wo[j];
                acc[8 + j] += xs * wi[j];
            }
        }
    }

    int gnode = base + t;
    if (gnode < BN) {
        float4* dst = (float4*)(P + ((size_t)gnode << 4));
        dst[0] = make_float4(acc[0],  acc[1],  acc[2],  acc[3]);
        dst[1] = make_float4(acc[4],  acc[5],  acc[6],  acc[7]);
        dst[2] = make_float4(acc[8],  acc[9],  acc[10], acc[11]);
        dst[3] = make_float4(acc[12], acc[13], acc[14], acc[15]);
    }
}

// Phase 2: per edge: h = tanh(P_o[ro] + P_i[ri]); out = sigmoid(h·W2 + b2)
// blockIdx.x & 7 == batch -> pins each batch's 3.2MB P-slice to one XCD's L2.
// 2 edges/thread, int2 index loads, float2 output stores (E is even).
__global__ __launch_bounds__(256) void phase2_kernel(
    const int* __restrict__ Ri, const int* __restrict__ Ro,
    const float* __restrict__ P, const float* __restrict__ W2,
    const float* __restrict__ b2, float* __restrict__ out,
    int E, int N) {
    int b = blockIdx.x & 7;
    int e0 = (((blockIdx.x >> 3) << 8) + threadIdx.x) * 2;
    if (e0 >= E) return;
    size_t idx0 = (size_t)b * E + e0;
    int2 ro2 = *(const int2*)(Ro + idx0);
    int2 ri2 = *(const int2*)(Ri + idx0);

    float4 w2a = *(const float4*)W2;                 // uniform -> s_load
    float4 w2b = *(const float4*)(W2 + 4);
    float bias2 = b2[0];
    const float4* Pv = (const float4*)P;
    int nb = b * N;

    float r[2];
#pragma unroll
    for (int k = 0; k < 2; ++k) {
        int ro = (k == 0) ? ro2.x : ro2.y;
        int ri = (k == 0) ? ri2.x : ri2.y;
        int robase = (nb + ro) << 2;                 // float4 units; P row = 4 f4
        int ribase = (nb + ri) << 2;
        float4 a0 = Pv[robase],     a1 = Pv[robase + 1];  // P_o(ro) (b1 folded)
        float4 c0 = Pv[ribase + 2], c1 = Pv[ribase + 3];  // P_i(ri)
        float s = bias2;
        s += fast_tanh(a0.x + c0.x) * w2a.x;
        s += fast_tanh(a0.y + c0.y) * w2a.y;
        s += fast_tanh(a0.z + c0.z) * w2a.z;
        s += fast_tanh(a0.w + c0.w) * w2a.w;
        s += fast_tanh(a1.x + c1.x) * w2b.x;
        s += fast_tanh(a1.y + c1.y) * w2b.y;
        s += fast_tanh(a1.z + c1.z) * w2b.z;
        s += fast_tanh(a1.w + c1.w) * w2b.w;
        r[k] = fast_sigmoid(s);
    }
    *(float2*)(out + idx0) = make_float2(r[0], r[1]);   // E even -> no tail
}

// Fallback if workspace is too small: one-pass per-edge evaluation.
__global__ __launch_bounds__(256) void direct_kernel(
    const float* __restrict__ X, const int* __restrict__ Ri, const int* __restrict__ Ro,
    const float* __restrict__ W1, const float* __restrict__ b1,
    const float* __restrict__ W2, const float* __restrict__ b2,
    float* __restrict__ out, int E, int N) {
    int b = blockIdx.x & 7;
    int e = ((blockIdx.x >> 3) << 8) + threadIdx.x;
    if (e >= E) return;
    size_t idx = (size_t)b * E + e;
    int ro = Ro[idx], ri = Ri[idx];
    const float* xo = X + (size_t)(b * N + ro) * 64;
    const float* xi = X + (size_t)(b * N + ri) * 64;
    float acc[8];
#pragma unroll
    for (int j = 0; j < 8; ++j) acc[j] = b1[j];
#pragma unroll
    for (int dc = 0; dc < 64; dc += 4) {
        float4 ov = *(const float4*)(xo + dc);
        float4 iv = *(const float4*)(xi + dc);
#pragma unroll
        for (int dd = 0; dd < 4; ++dd) {
            float os = (dd == 0) ? ov.x : (dd == 1) ? ov.y : (dd == 2) ? ov.z : ov.w;
            float is = (dd == 0) ? iv.x : (dd == 1) ? iv.y : (dd == 2) ? iv.z : iv.w;
            const float* wo = W1 + (dc + dd) * 8;
            const float* wi = W1 + (64 + dc + dd) * 8;
#pragma unroll
            for (int j = 0; j < 8; ++j)
                acc[j] += os * wo[j] + is * wi[j];
        }
    }
    float4 w2a = *(const float4*)W2;
    float4 w2b = *(const float4*)(W2 + 4);
    float w2v[8] = {w2a.x, w2a.y, w2a.z, w2a.w, w2b.x, w2b.y, w2b.z, w2b.w};
    float s = b2[0];
#pragma unroll
    for (int j = 0; j < 8; ++j) s += fast_tanh(acc[j]) * w2v[j];
    out[idx] = fast_sigmoid(s);
}

extern "C" void kernel_launch(void* const* d_in, const int* in_sizes, int n_in,
                              void* d_out, int out_size, void* d_ws, size_t ws_size,
                              hipStream_t stream) {
    const float* X  = (const float*)d_in[0];
    const int*   Ri = (const int*)d_in[1];
    const int*   Ro = (const int*)d_in[2];
    const float* W1 = (const float*)d_in[3];
    const float* b1 = (const float*)d_in[4];
    const float* W2 = (const float*)d_in[5];
    const float* b2 = (const float*)d_in[6];
    float* out = (float*)d_out;

    const int B = 8;
    const int N = in_sizes[0] / (B * 64);   // 50000
    const int E = in_sizes[1] / B;          // 200000
    const int BN = B * N;

    size_t needP = (size_t)BN * 16 * sizeof(float);

    if (ws_size >= needP) {
        float* P = (float*)d_ws;
        int g1 = (BN + TILE - 1) / TILE;
        phase1_kernel<<<g1, 256, 0, stream>>>(X, W1, b1, P, BN);
        int bpb2 = (E + 511) / 512;
        phase2_kernel<<<8 * bpb2, 256, 0, stream>>>(Ri, Ro, P, W2, b2, out, E, N);
    } else {
        int bpb = (E + 255) / 256;
        direct_kernel<<<8 * bpb, 256, 0, stream>>>(X, Ri, Ro, W1, b1, W2, b2, out, E, N);
    }
}

// Round 5
// 189.895 us; speedup vs baseline: 1.4272x; 1.0621x over previous
//
#include <hip/hip_runtime.h>
#include <hip/hip_bf16.h>

#define TILE 256   // nodes per block in phase 1

typedef float f32x4 __attribute__((ext_vector_type(4)));
typedef int   i32x4 __attribute__((ext_vector_type(4)));

__device__ __forceinline__ float fast_tanh(float x) {
    float ax = fabsf(x);
    float t = __expf(-2.f * ax);                       // in (0,1], no overflow
    float r = (1.f - t) * __builtin_amdgcn_rcpf(1.f + t);
    return copysignf(r, x);
}

__device__ __forceinline__ float fast_sigmoid(float s) {
    return __builtin_amdgcn_rcpf(1.f + __expf(-s));
}

// Phase 1: P[n][0:8] = X[n]·W1[0:64,:] + b1 ; P[n][8:16] = X[n]·W1[64:128,:]
// 32KB LDS (2 chunks of 128B per node row) -> 5 blocks/CU (20 waves/CU).
// XOR-swizzled [node][8] f32x4 layout: uniform-minimum banks on write & read.
// X loads are nontemporal (read-once; keep L2/L3 clean for P).
__global__ __launch_bounds__(256) void phase1_kernel(
    const float* __restrict__ X, const float* __restrict__ W1,
    const float* __restrict__ b1, float* __restrict__ P, int BN) {
    __shared__ f32x4 lds[TILE * 8];   // 32 KB
    int t = threadIdx.x;
    int base = blockIdx.x * TILE;

    float acc[16];
#pragma unroll
    for (int j = 0; j < 8; ++j) acc[j] = b1[j];      // uniform -> s_load
#pragma unroll
    for (int j = 8; j < 16; ++j) acc[j] = 0.f;

    const f32x4* Xv = (const f32x4*)X;
    int sw = t & 7;

#pragma unroll
    for (int c = 0; c < 2; ++c) {
        // Stage chunk c: 2048 f32x4, 8 per thread; each node contributes one
        // contiguous 128B half-row -> full-line global reads.
#pragma unroll
        for (int k = 0; k < 8; ++k) {
            int s = t + (k << 8);
            int node = s >> 3, f4l = s & 7;
            int gn = base + node;
            gn = (gn < BN) ? gn : (BN - 1);          // clamp: in-bounds
            f32x4 v = __builtin_nontemporal_load(
                Xv + ((size_t)gn << 4) + (c << 3) + f4l);
            lds[(node << 3) | (f4l ^ (node & 7))] = v;
        }
        __syncthreads();

        // Compute: thread t owns node (base + t); 32 dims this chunk.
        const f32x4* row = lds + (t << 3);
#pragma unroll
        for (int j8 = 0; j8 < 8; ++j8) {
            f32x4 xv = row[j8 ^ sw];                 // de-swizzle read
#pragma unroll
            for (int dd = 0; dd < 4; ++dd) {
                int d = (c << 5) + (j8 << 2) + dd;
                float xs = xv[dd];
                const float* wo = W1 + d * 8;        // uniform -> s_load
                const float* wi = W1 + (64 + d) * 8;
#pragma unroll
                for (int j = 0; j < 8; ++j) {
                    acc[j]     += xs * wo[j];
                    acc[8 + j] += xs * wi[j];
                }
            }
        }
        if (c == 0) __syncthreads();                 // before re-staging
    }

    int gnode = base + t;
    if (gnode < BN) {
        f32x4* dst = (f32x4*)(P + ((size_t)gnode << 4));
        dst[0] = f32x4{acc[0],  acc[1],  acc[2],  acc[3]};
        dst[1] = f32x4{acc[4],  acc[5],  acc[6],  acc[7]};
        dst[2] = f32x4{acc[8],  acc[9],  acc[10], acc[11]};
        dst[3] = f32x4{acc[12], acc[13], acc[14], acc[15]};
    }
}

// Phase 2: per edge: h = tanh(P_o[ro] + P_i[ri]); out = sigmoid(h·W2 + b2)
// blockIdx.x & 7 == batch -> pins each batch's 3.2MB P-slice to one XCD's L2.
// 4 edges/thread: int4 nt index loads, 16 gathers issued before any math,
// f32x4 nt output store (E % 4 == 0 -> no tail).
__global__ __launch_bounds__(256) void phase2_kernel(
    const int* __restrict__ Ri, const int* __restrict__ Ro,
    const float* __restrict__ P, const float* __restrict__ W2,
    const float* __restrict__ b2, float* __restrict__ out,
    int E, int N) {
    int b = blockIdx.x & 7;
    int e0 = (((blockIdx.x >> 3) << 8) + threadIdx.x) << 2;
    if (e0 >= E) return;
    size_t idx0 = (size_t)b * E + e0;
    i32x4 ro4 = __builtin_nontemporal_load((const i32x4*)(Ro + idx0));
    i32x4 ri4 = __builtin_nontemporal_load((const i32x4*)(Ri + idx0));

    const f32x4* Pv = (const f32x4*)P;
    int nb = b * N;
    f32x4 a0[4], a1[4], c0[4], c1[4];
#pragma unroll
    for (int k = 0; k < 4; ++k) {                    // all 16 gathers in flight
        int rb = (nb + ro4[k]) << 2;                 // f32x4 units; row = 4
        int ib = (nb + ri4[k]) << 2;
        a0[k] = Pv[rb];     a1[k] = Pv[rb + 1];      // P_o(ro) (b1 folded in)
        c0[k] = Pv[ib + 2]; c1[k] = Pv[ib + 3];      // P_i(ri)
    }

    f32x4 w2a = *(const f32x4*)W2;                   // uniform -> s_load
    f32x4 w2b = *(const f32x4*)(W2 + 4);
    float bias2 = b2[0];
    f32x4 res;
#pragma unroll
    for (int k = 0; k < 4; ++k) {
        float s = bias2;
#pragma unroll
        for (int j = 0; j < 4; ++j) {
            s += fast_tanh(a0[k][j] + c0[k][j]) * w2a[j];
            s += fast_tanh(a1[k][j] + c1[k][j]) * w2b[j];
        }
        res[k] = fast_sigmoid(s);
    }
    __builtin_nontemporal_store(res, (f32x4*)(out + idx0));
}

// Fallback if workspace is too small: one-pass per-edge evaluation.
__global__ __launch_bounds__(256) void direct_kernel(
    const float* __restrict__ X, const int* __restrict__ Ri, const int* __restrict__ Ro,
    const float* __restrict__ W1, const float* __restrict__ b1,
    const float* __restrict__ W2, const float* __restrict__ b2,
    float* __restrict__ out, int E, int N) {
    int b = blockIdx.x & 7;
    int e = ((blockIdx.x >> 3) << 8) + threadIdx.x;
    if (e >= E) return;
    size_t idx = (size_t)b * E + e;
    int ro = Ro[idx], ri = Ri[idx];
    const float* xo = X + (size_t)(b * N + ro) * 64;
    const float* xi = X + (size_t)(b * N + ri) * 64;
    float acc[8];
#pragma unroll
    for (int j = 0; j < 8; ++j) acc[j] = b1[j];
#pragma unroll
    for (int dc = 0; dc < 64; dc += 4) {
        float4 ov = *(const float4*)(xo + dc);
        float4 iv = *(const float4*)(xi + dc);
#pragma unroll
        for (int dd = 0; dd < 4; ++dd) {
            float os = (dd == 0) ? ov.x : (dd == 1) ? ov.y : (dd == 2) ? ov.z : ov.w;
            float is = (dd == 0) ? iv.x : (dd == 1) ? iv.y : (dd == 2) ? iv.z : iv.w;
            const float* wo = W1 + (dc + dd) * 8;
            const float* wi = W1 + (64 + dc + dd) * 8;
#pragma unroll
            for (int j = 0; j < 8; ++j)
                acc[j] += os * wo[j] + is * wi[j];
        }
    }
    float4 w2a = *(const float4*)W2;
    float4 w2b = *(const float4*)(W2 + 4);
    float w2v[8] = {w2a.x, w2a.y, w2a.z, w2a.w, w2b.x, w2b.y, w2b.z, w2b.w};
    float s = b2[0];
#pragma unroll
    for (int j = 0; j < 8; ++j) s += fast_tanh(acc[j]) * w2v[j];
    out[idx] = fast_sigmoid(s);
}

extern "C" void kernel_launch(void* const* d_in, const int* in_sizes, int n_in,
                              void* d_out, int out_size, void* d_ws, size_t ws_size,
                              hipStream_t stream) {
    const float* X  = (const float*)d_in[0];
    const int*   Ri = (const int*)d_in[1];
    const int*   Ro = (const int*)d_in[2];
    const float* W1 = (const float*)d_in[3];
    const float* b1 = (const float*)d_in[4];
    const float* W2 = (const float*)d_in[5];
    const float* b2 = (const float*)d_in[6];
    float* out = (float*)d_out;

    const int B = 8;
    const int N = in_sizes[0] / (B * 64);   // 50000
    const int E = in_sizes[1] / B;          // 200000
    const int BN = B * N;

    size_t needP = (size_t)BN * 16 * sizeof(float);

    if (ws_size >= needP) {
        float* P = (float*)d_ws;
        int g1 = (BN + TILE - 1) / TILE;
        phase1_kernel<<<g1, 256, 0, stream>>>(X, W1, b1, P, BN);
        int bpb2 = (E + 1023) / 1024;       // 4 edges/thread
        phase2_kernel<<<8 * bpb2, 256, 0, stream>>>(Ri, Ro, P, W2, b2, out, E, N);
    } else {
        int bpb = (E + 255) / 256;
        direct_kernel<<<8 * bpb, 256, 0, stream>>>(X, Ri, Ro, W1, b1, W2, b2, out, E, N);
    }
}